// Round 7
// baseline (222.382 us; speedup 1.0000x reference)
//
#include <hip/hip_runtime.h>

// VectorQuantizer: x[B=32,D=256,H=32,W=32] fp32, weight[K=1024,D=256] fp32.
// N = 32768 rows (NHWC). Per row: argmin_k d2(n,k) with *numpy-fp32 semantics*
// (proven R4/R5/R6 absmax=0): x2/w2 = numpy pairwise sums, dot = in-order fp32
// FMA chain, d2 = fl(fl(x2-2dot)+w2), argmin = first-min.
//
// R7: two fixes from R6 counters:
//  (a) vq_mfma spilled (VGPR_Count=84 vs 160-reg live set; WRITE_SIZE showed
//      +2MB scratch). Chunk shrunk 8->4 ntiles: af[2][8](64)+acc[2][4](32)
//      +bv[8](32) = 128 regs -> fits launch_bounds(256,3) cap (~170).
//  (b) vq_prep had 32 blocks (~60us on 256 CUs). Now 64 blocks x 16 rows,
//      pairwise w2 parallelized 16 threads/row over numpy's independent
//      (half,accumulator) slots -- bit-exact order preserved.

#define D_DIM 256
#define K_DIM 1024
#define HW    1024
#define N_ROWS 32768

#define M_BLK 32            // rows per block (2 MFMA m-tiles)
#define XSTR  257           // LDS row stride (floats): bank = (r + d) % 32
#define TAU_SEL 1.5e-3f     // candidate margin (>> 2*bf16 jitter ~7e-4)
#define LCAP 2048           // candidate list capacity per block

typedef __attribute__((ext_vector_type(8))) short short8;
typedef __attribute__((ext_vector_type(4))) float float4v;

// round-to-nearest-even fp32 -> bf16 bits
__device__ __forceinline__ short f2bf(float f) {
  unsigned u = __builtin_bit_cast(unsigned, f);
  u = u + 0x7FFFu + ((u >> 16) & 1u);
  return (short)(u >> 16);
}

// numpy pairwise_sum (n=256) of squares (R4-proven bit-exact recipe), serial.
__device__ __forceinline__ float np_sumsq_256(const float* base, int stride) {
  float half_sum[2];
#pragma unroll
  for (int h = 0; h < 2; ++h) {
    const float* a = base + h * 128 * stride;
    float r[8];
#pragma unroll
    for (int j = 0; j < 8; ++j) {
      float v = a[j * stride];
      r[j] = __fmul_rn(v, v);
    }
    for (int i = 8; i < 128; i += 8) {
#pragma unroll
      for (int j = 0; j < 8; ++j) {
        float v = a[(i + j) * stride];
        r[j] = __fadd_rn(r[j], __fmul_rn(v, v));
      }
    }
    half_sum[h] = __fadd_rn(
        __fadd_rn(__fadd_rn(r[0], r[1]), __fadd_rn(r[2], r[3])),
        __fadd_rn(__fadd_rn(r[4], r[5]), __fadd_rn(r[6], r[7])));
  }
  return __fadd_rn(half_sum[0], half_sum[1]);
}

// ---- prep: 64 blocks x 16 rows. Stage rows to LDS coalesced; emit bf16
// B-fragments (this block = 1 ntile) + exact pairwise w2 (16 thr/row). ----
__global__ __launch_bounds__(256) void vq_prep(
    const float* __restrict__ w, short8* __restrict__ wfrag,
    float* __restrict__ w2g) {
  __shared__ float wls[16 * XSTR];
  __shared__ float part[16 * 16];
  const int t = threadIdx.x;
  const int k0 = blockIdx.x * 16;
#pragma unroll
  for (int i = 0; i < 4; ++i) {
    int f = t + 256 * i;
    int r = f >> 6, c4 = f & 63;
    float4 v = *(const float4*)(w + (k0 + r) * D_DIM + c4 * 4);
    wls[r * XSTR + c4 * 4 + 0] = v.x;
    wls[r * XSTR + c4 * 4 + 1] = v.y;
    wls[r * XSTR + c4 * 4 + 2] = v.z;
    wls[r * XSTR + c4 * 4 + 3] = v.w;
  }
  __syncthreads();
  // w2 partials: thread (row, h, j) runs numpy's independent accumulator chain
  {
    int row = t >> 4, sl = t & 15, h = sl >> 3, j = sl & 7;
    const float* a = wls + row * XSTR + h * 128 + j;
    float r = __fmul_rn(a[0], a[0]);
    for (int i = 1; i < 16; ++i) {
      float v = a[8 * i];
      r = __fadd_rn(r, __fmul_rn(v, v));
    }
    part[row * 16 + sl] = r;
  }
  // frag pack: slot = ks*64 + lane, 2 per thread
#pragma unroll
  for (int i = 0; i < 2; ++i) {
    int slot = t + 256 * i;
    int lane = slot & 63, ks = slot >> 6;
    int ln15 = lane & 15, quad = lane >> 4;
    const float* src = wls + ln15 * XSTR + ks * 32 + quad * 8;
    short8 v;
#pragma unroll
    for (int j = 0; j < 8; ++j) v[j] = f2bf(src[j]);
    wfrag[(blockIdx.x * 8 + ks) * 64 + lane] = v;
  }
  __syncthreads();
  if (t < 16) {   // numpy combine, exact order
    const float* p = part + t * 16;
    float h0 = __fadd_rn(__fadd_rn(__fadd_rn(p[0], p[1]), __fadd_rn(p[2], p[3])),
                         __fadd_rn(__fadd_rn(p[4], p[5]), __fadd_rn(p[6], p[7])));
    float h1 = __fadd_rn(__fadd_rn(__fadd_rn(p[8], p[9]), __fadd_rn(p[10], p[11])),
                         __fadd_rn(__fadd_rn(p[12], p[13]), __fadd_rn(p[14], p[15])));
    w2g[k0 + t] = __fadd_rn(h0, h1);
  }
}

// ---- main: MFMA select + exact re-score + gather-write, all x via LDS ----
__global__ __launch_bounds__(256, 3) void vq_mfma(
    const float* __restrict__ x, const float* __restrict__ w,
    const short8* __restrict__ wfrag, const float* __restrict__ w2g,
    float* __restrict__ out) {
  __shared__ float xls[M_BLK * XSTR];     // x-tile [r][d], later winner w-rows
  __shared__ float w2s[K_DIM];
  __shared__ float x2s[M_BLK];
  __shared__ unsigned long long rowbest[M_BLK];
  __shared__ int list[LCAP];
  __shared__ int lcnt;

  const int t = threadIdx.x;
  const int lane = t & 63;
  const int wv = t >> 6;          // wave id = k-quarter
  const int quad = lane >> 4;
  const int ln15 = lane & 15;
  const int n0 = blockIdx.x * M_BLK;
  const int b = n0 >> 10;
  const int hw0 = n0 & 1023;
  const float* xb = x + b * (D_DIM * HW);   // index [d*HW + hw0 + r]

  if (t == 0) lcnt = 0;
  if (t < M_BLK) rowbest[t] = ~0ULL;
  for (int i = t; i < K_DIM; i += 256) w2s[i] = w2g[i];

  // stage x-tile coalesced: float4 over 4 consecutive rows at one d
#pragma unroll
  for (int i = 0; i < 8; ++i) {
    int f = t + 256 * i;
    int d = f >> 3, r4 = f & 7;
    float4 v = *(const float4*)(xb + d * HW + hw0 + r4 * 4);
    xls[(r4 * 4 + 0) * XSTR + d] = v.x;
    xls[(r4 * 4 + 1) * XSTR + d] = v.y;
    xls[(r4 * 4 + 2) * XSTR + d] = v.z;
    xls[(r4 * 4 + 3) * XSTR + d] = v.w;
  }
  __syncthreads();

  if (t < M_BLK) x2s[t] = np_sumsq_256(xls + t * XSTR, 1);

  // A-fragments from LDS: lane holds row m=lane&15, d = ks*32 + quad*8 + j
  short8 af[2][8];
#pragma unroll
  for (int mt = 0; mt < 2; ++mt) {
#pragma unroll
    for (int ks = 0; ks < 8; ++ks) {
      const float* xr = xls + (mt * 16 + ln15) * XSTR + ks * 32 + quad * 8;
      short8 v;
#pragma unroll
      for (int j = 0; j < 8; ++j) v[j] = f2bf(xr[j]);
      af[mt][ks] = v;
    }
  }

  // four n-chunks of 4 ntiles each (this wave's k-quarter = 16 ntiles)
  for (int c = 0; c < 4; ++c) {
    float4v acc[2][4];
#pragma unroll
    for (int mt = 0; mt < 2; ++mt)
#pragma unroll
      for (int nt = 0; nt < 4; ++nt)
        acc[mt][nt] = (float4v){0.f, 0.f, 0.f, 0.f};

#pragma unroll
    for (int nt = 0; nt < 4; ++nt) {
      const int ntg = wv * 16 + c * 4 + nt;
      short8 bv[8];
#pragma unroll
      for (int ks = 0; ks < 8; ++ks)
        bv[ks] = wfrag[(ntg * 8 + ks) * 64 + lane];
#pragma unroll
      for (int ks = 0; ks < 8; ++ks) {
        acc[0][nt] = __builtin_amdgcn_mfma_f32_16x16x32_bf16(af[0][ks], bv[ks], acc[0][nt], 0, 0, 0);
        acc[1][nt] = __builtin_amdgcn_mfma_f32_16x16x32_bf16(af[1][ks], bv[ks], acc[1][nt], 0, 0, 0);
      }
    }

    // chunk-local per-row min of sel = w2 - 2*dot
    // C/D layout (m89): col(code)=lane&15, row = quad*4 + reg
    float rmin[2][4];
#pragma unroll
    for (int mt = 0; mt < 2; ++mt)
#pragma unroll
      for (int rg = 0; rg < 4; ++rg) rmin[mt][rg] = 3.0e38f;
#pragma unroll
    for (int nt = 0; nt < 4; ++nt) {
      float w2v = w2s[wv * 256 + (c * 4 + nt) * 16 + ln15];
#pragma unroll
      for (int mt = 0; mt < 2; ++mt)
#pragma unroll
        for (int rg = 0; rg < 4; ++rg) {
          float s = fmaf(-2.f, acc[mt][nt][rg], w2v);
          rmin[mt][rg] = fminf(rmin[mt][rg], s);
        }
    }
#pragma unroll
    for (int mask = 1; mask < 16; mask <<= 1)
#pragma unroll
      for (int mt = 0; mt < 2; ++mt)
#pragma unroll
        for (int rg = 0; rg < 4; ++rg)
          rmin[mt][rg] = fminf(rmin[mt][rg], __shfl_xor(rmin[mt][rg], mask, 16));

    // flag candidates within TAU_SEL of chunk-min (superset of exact winner)
#pragma unroll
    for (int nt = 0; nt < 4; ++nt) {
      float w2v = w2s[wv * 256 + (c * 4 + nt) * 16 + ln15];
      int kk = wv * 256 + (c * 4 + nt) * 16 + ln15;
#pragma unroll
      for (int mt = 0; mt < 2; ++mt)
#pragma unroll
        for (int rg = 0; rg < 4; ++rg) {
          float s = fmaf(-2.f, acc[mt][nt][rg], w2v);
          if (s <= rmin[mt][rg] + TAU_SEL) {
            int r = mt * 16 + quad * 4 + rg;
            int pos = atomicAdd(&lcnt, 1);
            if (pos < LCAP) list[pos] = (r << 10) | kk;
          }
        }
    }
  }
  __syncthreads();

  // exact re-score (R4 bit-exact recipe) of flagged (r,k): x from LDS
  int cnt = lcnt; if (cnt > LCAP) cnt = LCAP;
  for (int i = t; i < cnt; i += 256) {
    int pk = list[i];
    int r = pk >> 10, k = pk & 1023;
    const float* wr = w + k * D_DIM;
    const float* xr = xls + r * XSTR;
    float a = 0.f;
    for (int d = 0; d < D_DIM; d += 8) {
      float4 w0 = *(const float4*)(wr + d);
      float4 w1 = *(const float4*)(wr + d + 4);
      a = __fmaf_rn(xr[d + 0], w0.x, a); a = __fmaf_rn(xr[d + 1], w0.y, a);
      a = __fmaf_rn(xr[d + 2], w0.z, a); a = __fmaf_rn(xr[d + 3], w0.w, a);
      a = __fmaf_rn(xr[d + 4], w1.x, a); a = __fmaf_rn(xr[d + 5], w1.y, a);
      a = __fmaf_rn(xr[d + 6], w1.z, a); a = __fmaf_rn(xr[d + 7], w1.w, a);
    }
    float d2 = __fadd_rn(__fsub_rn(x2s[r], __fmul_rn(2.0f, a)), w2s[k]);
    unsigned du = __builtin_bit_cast(unsigned, d2);     // d2 ~ 256 > 0: monotone
    unsigned long long key = ((unsigned long long)du << 32) | (unsigned)k;
    atomicMin(&rowbest[r], key);
  }
  __syncthreads();

  // gather: stage winner w-rows into LDS coalesced (wave reads 1KB contiguous)
#pragma unroll
  for (int i = 0; i < 8; ++i) {
    int f = t + 256 * i;
    int r = f >> 6, c4 = f & 63;
    int bk = (int)(rowbest[r] & 1023ULL);
    float4 v = *(const float4*)(w + bk * D_DIM + c4 * 4);
    xls[r * XSTR + c4 * 4 + 0] = v.x;
    xls[r * XSTR + c4 * 4 + 1] = v.y;
    xls[r * XSTR + c4 * 4 + 2] = v.z;
    xls[r * XSTR + c4 * 4 + 3] = v.w;
  }
  __syncthreads();

  // write out[b][d][hw0+r] = xls[r][d]; coalesced stores along r
  {
    float* ob = out + b * (D_DIM * HW) + hw0;
    int r = t & 31, dg = t >> 5;
#pragma unroll 4
    for (int i = 0; i < 32; ++i) {
      int d = dg * 32 + i;
      ob[d * HW + r] = xls[r * XSTR + d];
    }
  }
}

// ================= R4 fallback (proven exact) =================
#define TN  64
#define TKT 256
#define DCH 64
__global__ __launch_bounds__(256, 2) void vq_fallback(
    const float* __restrict__ x, const float* __restrict__ w,
    float* __restrict__ out) {
  __shared__ float xs[DCH * TN];
  __shared__ float ws[DCH * TKT];
  const int t  = threadIdx.x;
  const int kg = t & 31;
  const int rg = t >> 5;
  const int n0  = blockIdx.x * TN;
  const int b   = n0 >> 10;
  const int hw0 = n0 & 1023;
  const float* xb = x + b * (D_DIM * HW) + hw0;
  for (int kq = 0; kq < 4; ++kq) {
    int k = kq * 256 + t;
    xs[k] = np_sumsq_256(w + k * D_DIM, 1);
  }
  if (t < TN) ws[t] = np_sumsq_256(xb + t, HW);
  __syncthreads();
  float wq[4][8];
#pragma unroll
  for (int kti = 0; kti < 4; ++kti)
#pragma unroll
    for (int j = 0; j < 8; ++j) wq[kti][j] = xs[kti * 256 + kg * 8 + j];
  float x2r[8];
#pragma unroll
  for (int i = 0; i < 8; ++i) x2r[i] = ws[rg * 8 + i];
  float b1v[8]; int b1k[8];
#pragma unroll
  for (int i = 0; i < 8; ++i) { b1v[i] = 3.0e38f; b1k[i] = 0; }
  for (int kt = 0; kt < K_DIM; kt += TKT) {
    const int kti = kt >> 8;
    float acc[8][8];
#pragma unroll
    for (int i = 0; i < 8; ++i)
#pragma unroll
      for (int j = 0; j < 8; ++j) acc[i][j] = 0.f;
    for (int dc = 0; dc < D_DIM; dc += DCH) {
      __syncthreads();
#pragma unroll
      for (int i = 0; i < 4; ++i) {
        int f = t + 256 * i;
        int dd = f >> 4, r4 = f & 15;
        float4 v = *(const float4*)(xb + (dc + dd) * HW + r4 * 4);
        *(float4*)(xs + dd * TN + r4 * 4) = v;
      }
      {
        const float* wrow = w + (kt + t) * D_DIM + dc;
#pragma unroll
        for (int i = 0; i < 16; ++i) {
          float4 v = *(const float4*)(wrow + i * 4);
          ws[(i * 4 + 0) * TKT + t] = v.x;
          ws[(i * 4 + 1) * TKT + t] = v.y;
          ws[(i * 4 + 2) * TKT + t] = v.z;
          ws[(i * 4 + 3) * TKT + t] = v.w;
        }
      }
      __syncthreads();
#pragma unroll 2
      for (int dd = 0; dd < DCH; ++dd) {
        float4 xa = *(const float4*)(xs + dd * TN + rg * 8);
        float4 xc = *(const float4*)(xs + dd * TN + rg * 8 + 4);
        float4 wa = *(const float4*)(ws + dd * TKT + kg * 8);
        float4 wc = *(const float4*)(ws + dd * TKT + kg * 8 + 4);
        float xv[8] = {xa.x, xa.y, xa.z, xa.w, xc.x, xc.y, xc.z, xc.w};
        float wv[8] = {wa.x, wa.y, wa.z, wa.w, wc.x, wc.y, wc.z, wc.w};
#pragma unroll
        for (int i = 0; i < 8; ++i)
#pragma unroll
          for (int j = 0; j < 8; ++j)
            acc[i][j] = __fmaf_rn(xv[i], wv[j], acc[i][j]);
      }
    }
#pragma unroll
    for (int i = 0; i < 8; ++i)
#pragma unroll
      for (int j = 0; j < 8; ++j) {
        float t1 = __fsub_rn(x2r[i], __fmul_rn(2.0f, acc[i][j]));
        float d2 = __fadd_rn(t1, wq[kti][j]);
        int kk = kt + kg * 8 + j;
        if (d2 < b1v[i]) { b1v[i] = d2; b1k[i] = kk; }
      }
  }
  __syncthreads();
  float* rv1 = xs;
  int*   rk1 = (int*)(xs + 2048);
  int*   idxs = (int*)ws;
#pragma unroll
  for (int i = 0; i < 8; ++i) {
    int r = rg * 8 + i;
    rv1[r * 32 + kg] = b1v[i];
    rk1[r * 32 + kg] = b1k[i];
  }
  __syncthreads();
  if (t < TN) {
    float bv = rv1[t * 32]; int bk = rk1[t * 32];
    for (int j = 1; j < 32; ++j) {
      float v = rv1[t * 32 + j]; int ik = rk1[t * 32 + j];
      if (v < bv || (v == bv && ik < bk)) { bv = v; bk = ik; }
    }
    idxs[t] = bk;
  }
  __syncthreads();
  float* ob = out + b * (D_DIM * HW) + hw0;
  const int r  = t & 63;
  const int db = t >> 6;
  const int myk = idxs[r];
  const float* wrow = w + myk * D_DIM + db * 64;
#pragma unroll 4
  for (int i = 0; i < 64; ++i) {
    int d = db * 64 + i;
    ob[d * HW + r] = wrow[i];
  }
}

extern "C" void kernel_launch(void* const* d_in, const int* in_sizes, int n_in,
                              void* d_out, int out_size, void* d_ws, size_t ws_size,
                              hipStream_t stream) {
  const float* x = (const float*)d_in[0];
  const float* w = (const float*)d_in[1];
  float* out = (float*)d_out;
  const size_t need = (size_t)K_DIM * D_DIM * 2 + (size_t)K_DIM * 4;  // 516 KB
  if (ws_size < need) {
    vq_fallback<<<dim3(N_ROWS / TN), dim3(256), 0, stream>>>(x, w, out);
    return;
  }
  short8* wfrag = (short8*)d_ws;                          // 512 KB
  float*  w2g   = (float*)((char*)d_ws + (size_t)K_DIM * D_DIM * 2);
  vq_prep<<<dim3(K_DIM / 16), dim3(256), 0, stream>>>(w, wfrag, w2g);
  vq_mfma<<<dim3(N_ROWS / M_BLK), dim3(256), 0, stream>>>(x, w, wfrag, w2g, out);
}

// Round 8
// 155.127 us; speedup vs baseline: 1.4335x; 1.4335x over previous
//
#include <hip/hip_runtime.h>

// VectorQuantizer: x[B=32,D=256,H=32,W=32] fp32, weight[K=1024,D=256] fp32.
// N = 32768 rows (NHWC). Per row: argmin_k d2(n,k) with *numpy-fp32 semantics*
// (proven R4-R7 absmax=0): x2/w2 = numpy pairwise sums, dot = in-order fp32
// FMA chain, d2 = fl(fl(x2-2dot)+w2), argmin = first-min.
//
// R8 (from R7 counters: latency-bound, re-score loop = 32 serial L2 round
// trips per candidate x ~1300 candidates):
//  (a) store s with each flagged entry + compute per-row GLOBAL min; filter
//      re-score to s <= rowmin+TAU  (~1300 -> ~40 candidates).
//  (b) re-score preloads w-row in 4 batched sections of 16 float4 (pipelined
//      vmcnt) -- same ascending FMA order, bit-exact.
//  (c) MFMA loop: bv A/B double-buffer with static parity (unrolled chunks)
//      so next ntile's 8 L2 loads overlap current 16 MFMAs.
//      launch_bounds(256,2): ~200-reg live set, no spill.

#define D_DIM 256
#define K_DIM 1024
#define HW    1024
#define N_ROWS 32768

#define M_BLK 32            // rows per block (2 MFMA m-tiles)
#define XSTR  257           // LDS row stride (floats)
#define TAU_SEL 1.5e-3f     // candidate margin (>> 2*bf16 jitter ~7e-4)
#define LCAP 3072           // candidate list capacity per block

typedef __attribute__((ext_vector_type(8))) short short8;
typedef __attribute__((ext_vector_type(4))) float float4v;

// round-to-nearest-even fp32 -> bf16 bits
__device__ __forceinline__ short f2bf(float f) {
  unsigned u = __builtin_bit_cast(unsigned, f);
  u = u + 0x7FFFu + ((u >> 16) & 1u);
  return (short)(u >> 16);
}

// numpy pairwise_sum (n=256) of squares (R4-proven bit-exact recipe), serial.
__device__ __forceinline__ float np_sumsq_256(const float* base, int stride) {
  float half_sum[2];
#pragma unroll
  for (int h = 0; h < 2; ++h) {
    const float* a = base + h * 128 * stride;
    float r[8];
#pragma unroll
    for (int j = 0; j < 8; ++j) {
      float v = a[j * stride];
      r[j] = __fmul_rn(v, v);
    }
    for (int i = 8; i < 128; i += 8) {
#pragma unroll
      for (int j = 0; j < 8; ++j) {
        float v = a[(i + j) * stride];
        r[j] = __fadd_rn(r[j], __fmul_rn(v, v));
      }
    }
    half_sum[h] = __fadd_rn(
        __fadd_rn(__fadd_rn(r[0], r[1]), __fadd_rn(r[2], r[3])),
        __fadd_rn(__fadd_rn(r[4], r[5]), __fadd_rn(r[6], r[7])));
  }
  return __fadd_rn(half_sum[0], half_sum[1]);
}

// ---- prep: 64 blocks x 16 rows (1 ntile). LDS-staged coalesced; bf16
// B-fragments + exact pairwise w2 (16 thr/row, numpy order preserved). ----
__global__ __launch_bounds__(256) void vq_prep(
    const float* __restrict__ w, short8* __restrict__ wfrag,
    float* __restrict__ w2g) {
  __shared__ float wls[16 * XSTR];
  __shared__ float part[16 * 16];
  const int t = threadIdx.x;
  const int k0 = blockIdx.x * 16;
#pragma unroll
  for (int i = 0; i < 4; ++i) {
    int f = t + 256 * i;
    int r = f >> 6, c4 = f & 63;
    float4 v = *(const float4*)(w + (k0 + r) * D_DIM + c4 * 4);
    wls[r * XSTR + c4 * 4 + 0] = v.x;
    wls[r * XSTR + c4 * 4 + 1] = v.y;
    wls[r * XSTR + c4 * 4 + 2] = v.z;
    wls[r * XSTR + c4 * 4 + 3] = v.w;
  }
  __syncthreads();
  {
    int row = t >> 4, sl = t & 15, h = sl >> 3, j = sl & 7;
    const float* a = wls + row * XSTR + h * 128 + j;
    float r = __fmul_rn(a[0], a[0]);
    for (int i = 1; i < 16; ++i) {
      float v = a[8 * i];
      r = __fadd_rn(r, __fmul_rn(v, v));
    }
    part[row * 16 + sl] = r;
  }
#pragma unroll
  for (int i = 0; i < 2; ++i) {
    int slot = t + 256 * i;
    int lane = slot & 63, ks = slot >> 6;
    int ln15 = lane & 15, quad = lane >> 4;
    const float* src = wls + ln15 * XSTR + ks * 32 + quad * 8;
    short8 v;
#pragma unroll
    for (int j = 0; j < 8; ++j) v[j] = f2bf(src[j]);
    wfrag[(blockIdx.x * 8 + ks) * 64 + lane] = v;
  }
  __syncthreads();
  if (t < 16) {   // numpy combine, exact order
    const float* p = part + t * 16;
    float h0 = __fadd_rn(__fadd_rn(__fadd_rn(p[0], p[1]), __fadd_rn(p[2], p[3])),
                         __fadd_rn(__fadd_rn(p[4], p[5]), __fadd_rn(p[6], p[7])));
    float h1 = __fadd_rn(__fadd_rn(__fadd_rn(p[8], p[9]), __fadd_rn(p[10], p[11])),
                         __fadd_rn(__fadd_rn(p[12], p[13]), __fadd_rn(p[14], p[15])));
    w2g[k0 + t] = __fadd_rn(h0, h1);
  }
}

// ---- main: MFMA select + global-min filter + exact re-score + gather ----
__global__ __launch_bounds__(256, 2) void vq_mfma(
    const float* __restrict__ x, const float* __restrict__ w,
    const short8* __restrict__ wfrag, const float* __restrict__ w2g,
    float* __restrict__ out) {
  __shared__ float xls[M_BLK * XSTR];     // x-tile [r][d], later winner w-rows
  __shared__ float w2s[K_DIM];
  __shared__ float x2s[M_BLK];
  __shared__ float wavemin[4][M_BLK];
  __shared__ float rowmin[M_BLK];
  __shared__ unsigned long long rowbest[M_BLK];
  __shared__ int   list[LCAP];
  __shared__ float sval[LCAP];
  __shared__ int lcnt;

  const int t = threadIdx.x;
  const int lane = t & 63;
  const int wv = t >> 6;          // wave id = k-quarter
  const int quad = lane >> 4;
  const int ln15 = lane & 15;
  const int n0 = blockIdx.x * M_BLK;
  const int b = n0 >> 10;
  const int hw0 = n0 & 1023;
  const float* xb = x + b * (D_DIM * HW);   // index [d*HW + hw0 + r]

  if (t == 0) lcnt = 0;
  if (t < M_BLK) rowbest[t] = ~0ULL;
  for (int i = t; i < K_DIM; i += 256) w2s[i] = w2g[i];

  // stage x-tile coalesced
#pragma unroll
  for (int i = 0; i < 8; ++i) {
    int f = t + 256 * i;
    int d = f >> 3, r4 = f & 7;
    float4 v = *(const float4*)(xb + d * HW + hw0 + r4 * 4);
    xls[(r4 * 4 + 0) * XSTR + d] = v.x;
    xls[(r4 * 4 + 1) * XSTR + d] = v.y;
    xls[(r4 * 4 + 2) * XSTR + d] = v.z;
    xls[(r4 * 4 + 3) * XSTR + d] = v.w;
  }
  __syncthreads();

  if (t < M_BLK) x2s[t] = np_sumsq_256(xls + t * XSTR, 1);

  // A-fragments from LDS: lane holds row m=lane&15, d = ks*32 + quad*8 + j
  short8 af[2][8];
#pragma unroll
  for (int mt = 0; mt < 2; ++mt) {
#pragma unroll
    for (int ks = 0; ks < 8; ++ks) {
      const float* xr = xls + (mt * 16 + ln15) * XSTR + ks * 32 + quad * 8;
      short8 v;
#pragma unroll
      for (int j = 0; j < 8; ++j) v[j] = f2bf(xr[j]);
      af[mt][ks] = v;
    }
  }

  const int ntbase = wv * 16;
  short8 bvA[8], bvB[8];
#define FETCH_BV(dst, g)                                                \
  do {                                                                  \
    _Pragma("unroll")                                                   \
    for (int ks = 0; ks < 8; ++ks)                                      \
      dst[ks] = wfrag[((ntbase + (g)) * 8 + ks) * 64 + lane];           \
  } while (0)
#define MFMA_NT(bv, nt)                                                 \
  do {                                                                  \
    _Pragma("unroll")                                                   \
    for (int ks = 0; ks < 8; ++ks) {                                    \
      acc[0][nt] = __builtin_amdgcn_mfma_f32_16x16x32_bf16(             \
          af[0][ks], bv[ks], acc[0][nt], 0, 0, 0);                      \
      acc[1][nt] = __builtin_amdgcn_mfma_f32_16x16x32_bf16(             \
          af[1][ks], bv[ks], acc[1][nt], 0, 0, 0);                      \
    }                                                                   \
  } while (0)

  float rminAll[2][4];
#pragma unroll
  for (int mt = 0; mt < 2; ++mt)
#pragma unroll
    for (int rg = 0; rg < 4; ++rg) rminAll[mt][rg] = 3.0e38f;

  FETCH_BV(bvA, 0);
#pragma unroll
  for (int c = 0; c < 4; ++c) {
    float4v acc[2][4];
#pragma unroll
    for (int mt = 0; mt < 2; ++mt)
#pragma unroll
      for (int nt = 0; nt < 4; ++nt)
        acc[mt][nt] = (float4v){0.f, 0.f, 0.f, 0.f};

    // static A/B parity double-buffer: g = c*4 + nt
    FETCH_BV(bvB, c * 4 + 1);  MFMA_NT(bvA, 0);
    FETCH_BV(bvA, c * 4 + 2);  MFMA_NT(bvB, 1);
    FETCH_BV(bvB, c * 4 + 3);  MFMA_NT(bvA, 2);
    if (c < 3) FETCH_BV(bvA, c * 4 + 4);
    MFMA_NT(bvB, 3);

    // chunk-local per-row min of sel = w2 - 2*dot
    // C/D layout (m89): col(code)=lane&15, row = quad*4 + reg
    float rmin[2][4];
#pragma unroll
    for (int mt = 0; mt < 2; ++mt)
#pragma unroll
      for (int rg = 0; rg < 4; ++rg) rmin[mt][rg] = 3.0e38f;
#pragma unroll
    for (int nt = 0; nt < 4; ++nt) {
      float w2v = w2s[ntbase * 16 + (c * 4 + nt) * 16 + ln15];
#pragma unroll
      for (int mt = 0; mt < 2; ++mt)
#pragma unroll
        for (int rg = 0; rg < 4; ++rg) {
          float s = fmaf(-2.f, acc[mt][nt][rg], w2v);
          rmin[mt][rg] = fminf(rmin[mt][rg], s);
        }
    }
#pragma unroll
    for (int mask = 1; mask < 16; mask <<= 1)
#pragma unroll
      for (int mt = 0; mt < 2; ++mt)
#pragma unroll
        for (int rg = 0; rg < 4; ++rg)
          rmin[mt][rg] = fminf(rmin[mt][rg], __shfl_xor(rmin[mt][rg], mask, 16));

#pragma unroll
    for (int mt = 0; mt < 2; ++mt)
#pragma unroll
      for (int rg = 0; rg < 4; ++rg)
        rminAll[mt][rg] = fminf(rminAll[mt][rg], rmin[mt][rg]);

    // flag candidates within TAU_SEL of chunk-min (superset of exact winner)
#pragma unroll
    for (int nt = 0; nt < 4; ++nt) {
      float w2v = w2s[ntbase * 16 + (c * 4 + nt) * 16 + ln15];
      int kk = ntbase * 16 + (c * 4 + nt) * 16 + ln15;
#pragma unroll
      for (int mt = 0; mt < 2; ++mt)
#pragma unroll
        for (int rg = 0; rg < 4; ++rg) {
          float s = fmaf(-2.f, acc[mt][nt][rg], w2v);
          if (s <= rmin[mt][rg] + TAU_SEL) {
            int r = mt * 16 + quad * 4 + rg;
            int pos = atomicAdd(&lcnt, 1);
            if (pos < LCAP) { list[pos] = (r << 10) | kk; sval[pos] = s; }
          }
        }
    }
  }
#undef FETCH_BV
#undef MFMA_NT

  // per-row global min: rminAll already ln15-uniform; ln15==0 lanes publish
  if (ln15 == 0) {
#pragma unroll
    for (int mt = 0; mt < 2; ++mt)
#pragma unroll
      for (int rg = 0; rg < 4; ++rg)
        wavemin[wv][mt * 16 + quad * 4 + rg] = rminAll[mt][rg];
  }
  __syncthreads();
  if (t < M_BLK)
    rowmin[t] = fminf(fminf(wavemin[0][t], wavemin[1][t]),
                      fminf(wavemin[2][t], wavemin[3][t]));
  __syncthreads();

  // exact re-score (R4 bit-exact recipe) of globally-surviving candidates
  int cnt = lcnt; if (cnt > LCAP) cnt = LCAP;
  for (int i = t; i < cnt; i += 256) {
    int pk = list[i];
    int r = pk >> 10;
    if (sval[i] > rowmin[r] + TAU_SEL) continue;   // not a possible winner
    int k = pk & 1023;
    const float* wr = w + k * D_DIM;
    const float* xr = xls + r * XSTR;
    float a = 0.f;
#pragma unroll
    for (int sec = 0; sec < 4; ++sec) {
      float4 wb[16];
#pragma unroll
      for (int q = 0; q < 16; ++q)
        wb[q] = ((const float4*)wr)[sec * 16 + q];   // 16 loads batched in flight
      const float* xs2 = xr + sec * 64;
#pragma unroll
      for (int q = 0; q < 16; ++q) {                 // ascending d, single chain
        a = __fmaf_rn(xs2[q * 4 + 0], wb[q].x, a);
        a = __fmaf_rn(xs2[q * 4 + 1], wb[q].y, a);
        a = __fmaf_rn(xs2[q * 4 + 2], wb[q].z, a);
        a = __fmaf_rn(xs2[q * 4 + 3], wb[q].w, a);
      }
    }
    float d2 = __fadd_rn(__fsub_rn(x2s[r], __fmul_rn(2.0f, a)), w2s[k]);
    unsigned du = __builtin_bit_cast(unsigned, d2);     // d2 ~ 256 > 0: monotone
    unsigned long long key = ((unsigned long long)du << 32) | (unsigned)k;
    atomicMin(&rowbest[r], key);
  }
  __syncthreads();

  // gather: stage winner w-rows into LDS coalesced (wave reads 1KB contiguous)
#pragma unroll
  for (int i = 0; i < 8; ++i) {
    int f = t + 256 * i;
    int r = f >> 6, c4 = f & 63;
    int bk = (int)(rowbest[r] & 1023ULL);
    float4 v = *(const float4*)(w + bk * D_DIM + c4 * 4);
    xls[r * XSTR + c4 * 4 + 0] = v.x;
    xls[r * XSTR + c4 * 4 + 1] = v.y;
    xls[r * XSTR + c4 * 4 + 2] = v.z;
    xls[r * XSTR + c4 * 4 + 3] = v.w;
  }
  __syncthreads();

  // write out[b][d][hw0+r] = xls[r][d]; coalesced stores along r
  {
    float* ob = out + b * (D_DIM * HW) + hw0;
    int r = t & 31, dg = t >> 5;
#pragma unroll 4
    for (int i = 0; i < 32; ++i) {
      int d = dg * 32 + i;
      ob[d * HW + r] = xls[r * XSTR + d];
    }
  }
}

// ================= R4 fallback (proven exact) =================
#define TN  64
#define TKT 256
#define DCH 64
__global__ __launch_bounds__(256, 2) void vq_fallback(
    const float* __restrict__ x, const float* __restrict__ w,
    float* __restrict__ out) {
  __shared__ float xs[DCH * TN];
  __shared__ float ws[DCH * TKT];
  const int t  = threadIdx.x;
  const int kg = t & 31;
  const int rg = t >> 5;
  const int n0  = blockIdx.x * TN;
  const int b   = n0 >> 10;
  const int hw0 = n0 & 1023;
  const float* xb = x + b * (D_DIM * HW) + hw0;
  for (int kq = 0; kq < 4; ++kq) {
    int k = kq * 256 + t;
    xs[k] = np_sumsq_256(w + k * D_DIM, 1);
  }
  if (t < TN) ws[t] = np_sumsq_256(xb + t, HW);
  __syncthreads();
  float wq[4][8];
#pragma unroll
  for (int kti = 0; kti < 4; ++kti)
#pragma unroll
    for (int j = 0; j < 8; ++j) wq[kti][j] = xs[kti * 256 + kg * 8 + j];
  float x2r[8];
#pragma unroll
  for (int i = 0; i < 8; ++i) x2r[i] = ws[rg * 8 + i];
  float b1v[8]; int b1k[8];
#pragma unroll
  for (int i = 0; i < 8; ++i) { b1v[i] = 3.0e38f; b1k[i] = 0; }
  for (int kt = 0; kt < K_DIM; kt += TKT) {
    const int kti = kt >> 8;
    float acc[8][8];
#pragma unroll
    for (int i = 0; i < 8; ++i)
#pragma unroll
      for (int j = 0; j < 8; ++j) acc[i][j] = 0.f;
    for (int dc = 0; dc < D_DIM; dc += DCH) {
      __syncthreads();
#pragma unroll
      for (int i = 0; i < 4; ++i) {
        int f = t + 256 * i;
        int dd = f >> 4, r4 = f & 15;
        float4 v = *(const float4*)(xb + (dc + dd) * HW + r4 * 4);
        *(float4*)(xs + dd * TN + r4 * 4) = v;
      }
      {
        const float* wrow = w + (kt + t) * D_DIM + dc;
#pragma unroll
        for (int i = 0; i < 16; ++i) {
          float4 v = *(const float4*)(wrow + i * 4);
          ws[(i * 4 + 0) * TKT + t] = v.x;
          ws[(i * 4 + 1) * TKT + t] = v.y;
          ws[(i * 4 + 2) * TKT + t] = v.z;
          ws[(i * 4 + 3) * TKT + t] = v.w;
        }
      }
      __syncthreads();
#pragma unroll 2
      for (int dd = 0; dd < DCH; ++dd) {
        float4 xa = *(const float4*)(xs + dd * TN + rg * 8);
        float4 xc = *(const float4*)(xs + dd * TN + rg * 8 + 4);
        float4 wa = *(const float4*)(ws + dd * TKT + kg * 8);
        float4 wc = *(const float4*)(ws + dd * TKT + kg * 8 + 4);
        float xv[8] = {xa.x, xa.y, xa.z, xa.w, xc.x, xc.y, xc.z, xc.w};
        float wv[8] = {wa.x, wa.y, wa.z, wa.w, wc.x, wc.y, wc.z, wc.w};
#pragma unroll
        for (int i = 0; i < 8; ++i)
#pragma unroll
          for (int j = 0; j < 8; ++j)
            acc[i][j] = __fmaf_rn(xv[i], wv[j], acc[i][j]);
      }
    }
#pragma unroll
    for (int i = 0; i < 8; ++i)
#pragma unroll
      for (int j = 0; j < 8; ++j) {
        float t1 = __fsub_rn(x2r[i], __fmul_rn(2.0f, acc[i][j]));
        float d2 = __fadd_rn(t1, wq[kti][j]);
        int kk = kt + kg * 8 + j;
        if (d2 < b1v[i]) { b1v[i] = d2; b1k[i] = kk; }
      }
  }
  __syncthreads();
  float* rv1 = xs;
  int*   rk1 = (int*)(xs + 2048);
  int*   idxs = (int*)ws;
#pragma unroll
  for (int i = 0; i < 8; ++i) {
    int r = rg * 8 + i;
    rv1[r * 32 + kg] = b1v[i];
    rk1[r * 32 + kg] = b1k[i];
  }
  __syncthreads();
  if (t < TN) {
    float bv = rv1[t * 32]; int bk = rk1[t * 32];
    for (int j = 1; j < 32; ++j) {
      float v = rv1[t * 32 + j]; int ik = rk1[t * 32 + j];
      if (v < bv || (v == bv && ik < bk)) { bv = v; bk = ik; }
    }
    idxs[t] = bk;
  }
  __syncthreads();
  float* ob = out + b * (D_DIM * HW) + hw0;
  const int r  = t & 63;
  const int db = t >> 6;
  const int myk = idxs[r];
  const float* wrow = w + myk * D_DIM + db * 64;
#pragma unroll 4
  for (int i = 0; i < 64; ++i) {
    int d = db * 64 + i;
    ob[d * HW + r] = wrow[i];
  }
}

extern "C" void kernel_launch(void* const* d_in, const int* in_sizes, int n_in,
                              void* d_out, int out_size, void* d_ws, size_t ws_size,
                              hipStream_t stream) {
  const float* x = (const float*)d_in[0];
  const float* w = (const float*)d_in[1];
  float* out = (float*)d_out;
  const size_t need = (size_t)K_DIM * D_DIM * 2 + (size_t)K_DIM * 4;  // 516 KB
  if (ws_size < need) {
    vq_fallback<<<dim3(N_ROWS / TN), dim3(256), 0, stream>>>(x, w, out);
    return;
  }
  short8* wfrag = (short8*)d_ws;                          // 512 KB
  float*  w2g   = (float*)((char*)d_ws + (size_t)K_DIM * D_DIM * 2);
  vq_prep<<<dim3(K_DIM / 16), dim3(256), 0, stream>>>(w, wfrag, w2g);
  vq_mfma<<<dim3(N_ROWS / M_BLK), dim3(256), 0, stream>>>(x, w, wfrag, w2g, out);
}